// Round 7
// baseline (1528.900 us; speedup 1.0000x reference)
//
#include <hip/hip_runtime.h>
#include <stdint.h>

#define BB 128
#define SS 2048
#define TT 128
#define NSEG 32
#define SEGK 64
#define CHK 32               // e-chunk rows / hist-stage rows

// padded layouts (bank-conflict-free, validated R4)
#define TRP 129              // trans row stride (129 % 32 == 1)
#define VSTRIDE 136          // state buffer stride
#define H1OFF 68             // half-1 offset (68 % 32 == 4 -> disjoint banks vs half-0)

typedef float f32x4 __attribute__((ext_vector_type(4)));

// raw barrier: drain LDS ops only (NOT vmcnt -> no store-ack serialization)
#define BAR() asm volatile("s_waitcnt lgkmcnt(0)\n\ts_barrier" ::: "memory")
#define PIN(x) asm volatile("" : "+v"(x))

__device__ __forceinline__ float dpp_swap1_f(float x) {
    int i = __float_as_int(x);
    i = __builtin_amdgcn_update_dpp(0, i, 0xB1, 0xF, 0xF, true);
    return __int_as_float(i);
}
__device__ __forceinline__ int dpp_swap1_i(int x) {
    return __builtin_amdgcn_update_dpp(0, x, 0xB1, 0xF, 0xF, true);
}

// one viterbi step: NO VMEM. e from LDS chunk, hist staged to LDS.
#define VSTEP(slot, CURP)                                                     \
{                                                                             \
    const int cur_ = (CURP), nxt_ = 1 - cur_;                                 \
    const float e_ = ecur[(slot) * TT + j];                                   \
    const f32x4* sq_ = (const f32x4*)(vecLDS + cur_ * VSTRIDE + h * H1OFF);   \
    float cm_[8];                                                             \
    _Pragma("unroll")                                                         \
    for (int c = 0; c < 8; ++c) {                                             \
        f32x4 pa = sq_[2 * c] + tC[2 * c];                                    \
        f32x4 pb = sq_[2 * c + 1] + tC[2 * c + 1];                            \
        float m01 = fmaxf(pa.x, pa.y), m23 = fmaxf(pa.z, pa.w);               \
        float m45 = fmaxf(pb.x, pb.y), m67 = fmaxf(pb.z, pb.w);               \
        cm_[c] = fmaxf(fmaxf(m01, m23), fmaxf(m45, m67));                     \
    }                                                                         \
    float M_ = fmaxf(fmaxf(fmaxf(cm_[0], cm_[1]), fmaxf(cm_[2], cm_[3])),     \
                     fmaxf(fmaxf(cm_[4], cm_[5]), fmaxf(cm_[6], cm_[7])));    \
    const float Mall_ = fmaxf(M_, dpp_swap1_f(M_));                           \
    const float v_ = Mall_ + e_;   /* exact reference max value */            \
    int cwin_ = -1;                                                           \
    _Pragma("unroll")                                                         \
    for (int c = 7; c >= 0; --c) cwin_ = ((cm_[c] + e_) == v_) ? c : cwin_;   \
    int idx_ = 0x7fffffff;                                                    \
    if (cwin_ >= 0) {                                                         \
        const int basei_ = ibase0 + cwin_ * 8;                                \
        const float* tr_ = transLDS + (size_t)basei_ * TRP + j;               \
        const f32x4* sr_ = (const f32x4*)(vecLDS + cur_ * VSTRIDE + h * H1OFF + cwin_ * 8); \
        f32x4 ra_ = sr_[0], rb_ = sr_[1];                                     \
        float q0 = (ra_.x + tr_[0 * TRP]) + e_;                               \
        float q1 = (ra_.y + tr_[1 * TRP]) + e_;                               \
        float q2 = (ra_.z + tr_[2 * TRP]) + e_;                               \
        float q3 = (ra_.w + tr_[3 * TRP]) + e_;                               \
        float q4 = (rb_.x + tr_[4 * TRP]) + e_;                               \
        float q5 = (rb_.y + tr_[5 * TRP]) + e_;                               \
        float q6 = (rb_.z + tr_[6 * TRP]) + e_;                               \
        float q7 = (rb_.w + tr_[7 * TRP]) + e_;                               \
        idx_ = (q7 == v_) ? basei_ + 7 : idx_;                                \
        idx_ = (q6 == v_) ? basei_ + 6 : idx_;                                \
        idx_ = (q5 == v_) ? basei_ + 5 : idx_;                                \
        idx_ = (q4 == v_) ? basei_ + 4 : idx_;                                \
        idx_ = (q3 == v_) ? basei_ + 3 : idx_;                                \
        idx_ = (q2 == v_) ? basei_ + 2 : idx_;                                \
        idx_ = (q1 == v_) ? basei_ + 1 : idx_;                                \
        idx_ = (q0 == v_) ? basei_ + 0 : idx_;                                \
    }                                                                         \
    const int oidx_ = dpp_swap1_i(idx_);                                      \
    idx_ = (oidx_ < idx_) ? oidx_ : idx_;  /* first-index across halves */    \
    if (h == 0) {                                                             \
        vecLDS[nxt_ * VSTRIDE + joff] = v_;                                   \
        hsLDS[(slot) * TT + j] = (uint8_t)idx_;                               \
    }                                                                         \
    BAR();                                                                    \
}

// one forward step: NO VMEM
#define FSTEP(slot, CURP)                                                     \
{                                                                             \
    const int cur_ = (CURP), nxt_ = 1 - cur_;                                 \
    const int tt_ = tc + (slot);                                              \
    const float Rcons_ = ringLDS[(tt_ - 3) & 3];                              \
    const float Rpub_  = ringLDS[(tt_ - 2) & 3];                              \
    const float e_ = ecur[(slot) * TT + j];                                   \
    const f32x4* aq_ = (const f32x4*)(vecLDS + cur_ * VSTRIDE + h * H1OFF);   \
    f32x4 s4_ = {0.f, 0.f, 0.f, 0.f}, s4b_ = {0.f, 0.f, 0.f, 0.f};            \
    _Pragma("unroll")                                                         \
    for (int c = 0; c < 16; c += 2) {                                         \
        s4_  = aq_[c] * tE[c] + s4_;                                          \
        s4b_ = aq_[c + 1] * tE[c + 1] + s4b_;                                 \
    }                                                                         \
    f32x4 st_ = s4_ + s4b_;                                                   \
    float Ssum_ = (st_.x + st_.y) + (st_.z + st_.w);                          \
    Ssum_ += dpp_swap1_f(Ssum_);                                              \
    alpha = e_ + Rcons_ + __logf(Ssum_);                                      \
    const float p_ = __expf(alpha - Rpub_);                                   \
    if (h == 0) vecLDS[nxt_ * VSTRIDE + joff] = p_;                           \
    if (tid == 0) ringLDS[tt_ & 3] = alpha;                                   \
    BAR();                                                                    \
}

// load chunk rows [s0, s0+CHK) into 4 regs (clamped to array end)
#define ECHUNK_LOAD(s0)                                                       \
{                                                                             \
    _Pragma("unroll")                                                         \
    for (int p = 0; p < 4; ++p) {                                             \
        int f = p * 1024 + tid * 4;                                           \
        int gf = (s0) * TT + f;                                               \
        int mx = (SS - 1) * TT + (f & (TT - 1));                              \
        gf = (gf < mx) ? gf : mx;                                             \
        ec[p] = *(const f32x4*)(logit + lbase + gf);                          \
    }                                                                         \
}
#define ECHUNK_STORE(dstbuf)                                                  \
{                                                                             \
    _Pragma("unroll")                                                         \
    for (int p = 0; p < 4; ++p)                                               \
        *(f32x4*)((dstbuf) + p * 1024 + tid * 4) = ec[p];                     \
}

// ---------------- main kernel: 256 blocks. role 0 = viterbi, role 1 = forward+num.
// 256 threads: j=tid>>1, h=tid&1 owns i-half [64h,64h+64). ----------------
__attribute__((amdgpu_flat_work_group_size(256, 256)))
__attribute__((amdgpu_waves_per_eu(1, 1)))
__global__ void crf_mainX(const float* __restrict__ logit,
                          const int* __restrict__ seq_lens,
                          const float* __restrict__ trans,
                          const float* __restrict__ startT,
                          const float* __restrict__ endT,
                          const int* __restrict__ target,
                          uint8_t* __restrict__ histG,
                          float* __restrict__ scr_logZ,
                          int* __restrict__ scr_last,
                          float* __restrict__ scr_num)
{
    extern __shared__ float smem[];
    float* transLDS = smem;                         // 16512 floats
    float* vecLDS   = smem + 16512;                 // 2 * VSTRIDE = 272
    float* ringLDS  = smem + 16512 + 272;           // 4
    float* redLDS   = smem + 16512 + 276;           // 8
    int*   redILDS  = (int*)(smem + 16512 + 284);   // 4
    float* sumLDS   = smem + 16512 + 288;           // 4  -> base used = 16804
    float* eLDS     = smem + 16804;                 // 2 * CHK*TT = 8192 floats
    uint8_t* hsLDS  = (uint8_t*)(smem + 16804 + 8192);  // CHK*TT = 4096 bytes

    const int bid = blockIdx.x;
    const int role = bid >> 7;
    const int b = bid & (BB - 1);
    const int tid = threadIdx.x;
    const int j = tid >> 1;
    const int h = tid & 1;
    const int ibase0 = h << 6;
    const int joff = j + ((j >= 64) ? (H1OFF - 64) : 0);
    const int L = seq_lens[b];
    const size_t lbase = (size_t)b * (SS * TT);

    f32x4 ec[4];

    // prologue: stage chunk0 (rows [1, 1+CHK)) into eLDS buf0
    ECHUNK_LOAD(1);
    ECHUNK_STORE(eLDS);

    // stage transitions into padded LDS (stride TRP)
    for (int m = tid; m < TT * TT; m += 256)
        transLDS[(m >> 7) * TRP + (m & 127)] = trans[m];
    __syncthreads();   // full drain: echunk0 + trans staged, visible

    if (role == 0) {
        // =================== VITERBI ===================
        f32x4 tC[16];  // trans[i][j] for my i-half, pinned in VGPRs
#pragma unroll
        for (int c = 0; c < 16; ++c) {
            tC[c].x = transLDS[(ibase0 + c * 4 + 0) * TRP + j];
            tC[c].y = transLDS[(ibase0 + c * 4 + 1) * TRP + j];
            tC[c].z = transLDS[(ibase0 + c * 4 + 2) * TRP + j];
            tC[c].w = transLDS[(ibase0 + c * 4 + 3) * TRP + j];
            PIN(tC[c]);
        }
        const float a0 = startT[j] + logit[lbase + j];
        if (h == 0) vecLDS[joff] = a0;
        __syncthreads();

        uint8_t* hb = histG + (size_t)b * (SS * TT);

        int c = 0;
        for (int tc = 1; tc < L; tc += CHK, ++c) {
            const int tend = (tc + CHK < L) ? tc + CHK : L;
            const int n = tend - tc;
            const float* ecur = eLDS + (c & 1) * (CHK * TT);
            const bool more = (tc + CHK) < L;
            if (more) ECHUNK_LOAD(tc + CHK);   // 32 steps of latency slack

            // steps (tc is always odd -> parity = slot&1)
            for (int s = 0; s + 1 < n; s += 2) { VSTEP(s, 0); VSTEP(s + 1, 1); }
            if (n & 1) { VSTEP(n - 1, 0); }
            // (last VSTEP ended with BAR -> staging/state writes visible)

            // flush staged hist rows [tc, tend) -- coalesced dwordx4
            {
                const int lr = tid >> 3, cq = (tid & 7) * 16;
                if (lr < n) {
                    uint4 v = *(const uint4*)(hsLDS + lr * TT + cq);
                    *(uint4*)(hb + (size_t)(tc + lr) * TT + cq) = v;
                }
            }
            if (more) ECHUNK_STORE(eLDS + ((c + 1) & 1) * (CHK * TT));
            BAR();   // hsLDS reusable, next e-chunk visible
        }

        // ---- last_tag = argmax_j(score + end), first-index ----
        const int fin = (L - 1) & 1;
        if (tid < 128) {
            const int toff = tid + ((tid >= 64) ? (H1OFF - 64) : 0);
            float lv = vecLDS[fin * VSTRIDE + toff] + endT[tid];
            int li = tid;
#pragma unroll
            for (int off = 1; off < 64; off <<= 1) {
                float ov = __shfl_xor(lv, off);
                int oi = __shfl_xor(li, off);
                if (ov > lv || (ov == lv && oi < li)) { lv = ov; li = oi; }
            }
            if ((tid & 63) == 0) { redLDS[tid >> 6] = lv; redILDS[tid >> 6] = li; }
        }
        __syncthreads();
        if (tid == 0) {
            int lt = (redLDS[1] > redLDS[0] ||
                      (redLDS[1] == redLDS[0] && redILDS[1] < redILDS[0]))
                     ? redILDS[1] : redILDS[0];
            scr_last[b] = lt;
        }
        // ---- identity fill of hist rows [L, SS) ----
        const int colq = (tid & 7) * 16;
        const uint32_t w0 = 0x03020100u + 0x01010101u * (uint32_t)colq;
        const uint4 pat = make_uint4(w0, w0 + 0x04040404u, w0 + 0x08080808u, w0 + 0x0C0C0C0Cu);
        for (int t0 = L; t0 < SS; t0 += 32) {
            int tt = t0 + (tid >> 3);
            if (tt < SS) *(uint4*)(hb + (size_t)tt * TT + colq) = pat;
        }
    } else {
        // =================== FORWARD (logZ) ===================
        f32x4 tE[16];  // exp(trans[i][j]), pinned
#pragma unroll
        for (int c = 0; c < 16; ++c) {
            tE[c].x = __expf(transLDS[(ibase0 + c * 4 + 0) * TRP + j]);
            tE[c].y = __expf(transLDS[(ibase0 + c * 4 + 1) * TRP + j]);
            tE[c].z = __expf(transLDS[(ibase0 + c * 4 + 2) * TRP + j]);
            tE[c].w = __expf(transLDS[(ibase0 + c * 4 + 3) * TRP + j]);
            PIN(tE[c]);
        }
        const float a0 = startT[j] + logit[lbase + j];
        const float R0 = startT[0] + logit[lbase + 0];  // alpha0[0], uniform
        float alpha = a0;
        if (h == 0) vecLDS[joff] = __expf(a0 - R0);
        if (tid < 4) ringLDS[tid] = R0;
        __syncthreads();

        int c = 0;
        for (int tc = 1; tc < L; tc += CHK, ++c) {
            const int tend = (tc + CHK < L) ? tc + CHK : L;
            const int n = tend - tc;
            const float* ecur = eLDS + (c & 1) * (CHK * TT);
            const bool more = (tc + CHK) < L;
            if (more) ECHUNK_LOAD(tc + CHK);

            for (int s = 0; s + 1 < n; s += 2) { FSTEP(s, 0); FSTEP(s + 1, 1); }
            if (n & 1) { FSTEP(n - 1, 0); }

            if (more) ECHUNK_STORE(eLDS + ((c + 1) & 1) * (CHK * TT));
            BAR();
        }

        // ---- logZ epilogue (exact max) ----
        const float fval = alpha + endT[j];
        float tmx = fval;
#pragma unroll
        for (int off = 1; off < 64; off <<= 1) tmx = fmaxf(tmx, __shfl_xor(tmx, off));
        if ((tid & 63) == 0) redLDS[4 + (tid >> 6)] = tmx;
        __syncthreads();
        const float gm = fmaxf(fmaxf(redLDS[4], redLDS[5]), fmaxf(redLDS[6], redLDS[7]));
        float se = (h == 0) ? __expf(fval - gm) : 0.f;
#pragma unroll
        for (int off = 1; off < 64; off <<= 1) se += __shfl_xor(se, off);
        if ((tid & 63) == 0) sumLDS[tid >> 6] = se;
        __syncthreads();
        if (tid == 0)
            scr_logZ[b] = gm + __logf(sumLDS[0] + sumLDS[1] + sumLDS[2] + sumLDS[3]);
        __syncthreads();

        // ---- numerator (gold path score) ----
        float acc = 0.f;
        for (int tt = tid; tt < L; tt += 256) {
            int tg = target[b * SS + tt];
            acc += logit[((size_t)b * SS + tt) * TT + tg];
            if (tt >= 1) acc += trans[target[b * SS + tt - 1] * TT + tg];
        }
#pragma unroll
        for (int off = 1; off < 64; off <<= 1) acc += __shfl_xor(acc, off);
        if ((tid & 63) == 0) sumLDS[tid >> 6] = acc;
        __syncthreads();
        if (tid == 0) {
            float tot = sumLDS[0] + sumLDS[1] + sumLDS[2] + sumLDS[3];
            tot += startT[target[b * SS]] + endT[target[b * SS + L - 1]];
            scr_num[b] = tot;
        }
    }
}

// ---------------- phase 2: per-segment parallel backtrace of all 128 end-tags ----------------
__global__ void crf_btseg(uint8_t* __restrict__ histG)
{
    const int c = blockIdx.x;    // segment 0..31
    const int b = blockIdx.y;    // batch
    const int tid = threadIdx.x; // 128
    __shared__ __align__(16) uint8_t hl[SEGK * TT];

    const int lo = (c == 0) ? 1 : c * SEGK;
    const int nr = (c == 0) ? 63 : 64;
    const uint8_t* src = histG + (size_t)b * (SS * TT) + (size_t)lo * TT;
    for (int k = tid; k < (nr * TT) / 16; k += 128)
        ((uint4*)hl)[k] = ((const uint4*)src)[k];
    __syncthreads();

    int tau = tid;
    uint32_t w[16];
#pragma unroll
    for (int q = 0; q < 16; ++q) w[q] = 0u;
    if (c == 0) {
#pragma unroll
        for (int r = 62; r >= 0; --r) {
            tau = hl[r * TT + tau];
            w[r >> 2] |= ((uint32_t)tau) << ((r & 3) * 8);
        }
    } else {
#pragma unroll
        for (int r = 63; r >= 0; --r) {
            tau = hl[r * TT + tau];
            w[r >> 2] |= ((uint32_t)tau) << ((r & 3) * 8);
        }
    }
    uint4* dst = (uint4*)(histG + (size_t)b * (SS * TT) + (size_t)c * 8192 + (size_t)tid * 64);
    dst[0] = make_uint4(w[0], w[1], w[2], w[3]);
    dst[1] = make_uint4(w[4], w[5], w[6], w[7]);
    dst[2] = make_uint4(w[8], w[9], w[10], w[11]);
    dst[3] = make_uint4(w[12], w[13], w[14], w[15]);
}

// ---------------- phase 3: serial chain over 32 segment maps per batch ----------------
__global__ void crf_btchain(const uint8_t* __restrict__ histG,
                            const int* __restrict__ scr_last,
                            int* __restrict__ scr_bt,
                            float* __restrict__ out_pred)
{
    const int b = threadIdx.x;
    if (b >= BB) return;
    int tau = scr_last[b];
    out_pred[(size_t)b * SS + (SS - 1)] = (float)tau;
    for (int c = NSEG - 1; c >= 0; --c) {
        scr_bt[b * NSEG + c] = tau;
        tau = histG[(size_t)b * (SS * TT) + (size_t)c * 8192 + (size_t)tau * 64];
    }
}

// ---------------- phase 4: parallel fill of pred from chosen paths ----------------
__global__ void crf_btfill(const uint8_t* __restrict__ histG,
                           const int* __restrict__ scr_bt,
                           float* __restrict__ out_pred)
{
    const int c = blockIdx.x;
    const int b = blockIdx.y;
    const int s = threadIdx.x;   // 64
    if (c == 0 && s > 62) return;
    const int js = scr_bt[b * NSEG + c];
    uint8_t v = histG[(size_t)b * (SS * TT) + (size_t)c * 8192 + (size_t)js * 64 + s];
    const int pos = (c == 0) ? s : (c * SEGK - 1 + s);
    out_pred[(size_t)b * SS + pos] = (float)v;
}

// ---------------- loss = mean(logZ - num) ----------------
__global__ void crf_loss(const float* __restrict__ scr_logZ, const float* __restrict__ scr_num,
                         float* __restrict__ out)
{
    const int tid = threadIdx.x; // 128
    __shared__ float p2[2];
    float v = (tid < BB) ? (scr_logZ[tid] - scr_num[tid]) : 0.0f;
#pragma unroll
    for (int off = 1; off < 64; off <<= 1) v += __shfl_xor(v, off);
    if ((tid & 63) == 0) p2[tid >> 6] = v;
    __syncthreads();
    if (tid == 0) out[0] = (p2[0] + p2[1]) / (float)BB;
}

// ---------------- log_probs: swap + log_softmax, one wave per row ----------------
__global__ void crf_logprobs(const float* __restrict__ logit,
                             const float* __restrict__ predF,
                             float* __restrict__ outLP)
{
    const int wid = threadIdx.x >> 6;
    const int lane = threadIdx.x & 63;
    const size_t row = (size_t)blockIdx.x * 4 + wid;
    const float2* rp = (const float2*)(logit + row * TT);
    float2 v = rp[lane];
    const int pred = (int)predF[row];

    float mv; int mi;
    if (v.y > v.x) { mv = v.y; mi = lane * 2 + 1; }
    else           { mv = v.x; mi = lane * 2; }
#pragma unroll
    for (int off = 1; off < 64; off <<= 1) {
        float ov = __shfl_xor(mv, off);
        int oi = __shfl_xor(mi, off);
        if (ov > mv || (ov == mv && oi < mi)) { mv = ov; mi = oi; }
    }
    float se = __expf(v.x - mv) + __expf(v.y - mv);
#pragma unroll
    for (int off = 1; off < 64; off <<= 1) se += __shfl_xor(se, off);
    const float lse = __logf(se);

    float px = __shfl(v.x, pred >> 1);
    float py = __shfl(v.y, pred >> 1);
    float vp = (pred & 1) ? py : px;

    float ox = (lane * 2 == pred) ? mv : ((lane * 2 == mi) ? vp : v.x);
    float oy = (lane * 2 + 1 == pred) ? mv : ((lane * 2 + 1 == mi) ? vp : v.y);
    float* op = outLP + row * TT + lane * 2;
    op[0] = (ox - mv) - lse;
    op[1] = (oy - mv) - lse;
}

extern "C" void kernel_launch(void* const* d_in, const int* in_sizes, int n_in,
                              void* d_out, int out_size, void* d_ws, size_t ws_size,
                              hipStream_t stream)
{
    const float* logit    = (const float*)d_in[0];
    const int*   target   = (const int*)d_in[1];
    const int*   seq_lens = (const int*)d_in[2];
    const float* trans    = (const float*)d_in[3];
    const float* startT   = (const float*)d_in[4];
    const float* endT     = (const float*)d_in[5];

    float* out      = (float*)d_out;
    float* out_pred = out + 1;
    float* outLP    = out + 1 + (size_t)BB * SS;                 // 262145
    uint8_t* histG  = (uint8_t*)(out + 262148);                  // 16B-aligned, 33.5MB
    float* scr      = out + ((size_t)1 + (size_t)BB * SS + (size_t)BB * SS * TT - 4480);
    float* scr_logZ = scr;                // 128
    float* scr_num  = scr + 128;          // 128
    int*   scr_last = (int*)(scr + 256);  // 128
    int*   scr_bt   = (int*)(scr + 384);  // 128*32

    const int dynLDS = (16804 + 2 * CHK * TT + (CHK * TT) / 4) * 4;  // 104080 B
    hipFuncSetAttribute((const void*)crf_mainX,
                        hipFuncAttributeMaxDynamicSharedMemorySize, dynLDS);

    crf_mainX<<<2 * BB, 256, dynLDS, stream>>>(logit, seq_lens, trans, startT, endT,
                                               target, histG, scr_logZ, scr_last, scr_num);
    crf_btseg<<<dim3(NSEG, BB), 128, 0, stream>>>(histG);
    crf_btchain<<<1, 128, 0, stream>>>(histG, scr_last, scr_bt, out_pred);
    crf_btfill<<<dim3(NSEG, BB), 64, 0, stream>>>(histG, scr_bt, out_pred);
    crf_loss<<<1, 128, 0, stream>>>(scr_logZ, scr_num, out);
    crf_logprobs<<<(BB * SS) / 4, 256, 0, stream>>>(logit, out_pred, outLP);
}